// Round 7
// baseline (506.923 us; speedup 1.0000x reference)
//
#include <hip/hip_runtime.h>

#define NN 30000
#define NE 300000
#define HIDDEN 256

typedef __attribute__((ext_vector_type(8))) __bf16 bf16x8;
typedef __attribute__((ext_vector_type(4))) __bf16 bf16x4;
typedef __attribute__((ext_vector_type(4))) float float4v;

__device__ inline __bf16 f2bf(float f) {
  unsigned u = __builtin_bit_cast(unsigned, f);
  u += 0x7fffu + ((u >> 16) & 1u);
  unsigned short s = (unsigned short)(u >> 16);
  return __builtin_bit_cast(__bf16, s);
}
__device__ inline float bf2f(__bf16 b) {
  unsigned short s = __builtin_bit_cast(unsigned short, b);
  unsigned u = ((unsigned)s) << 16;
  return __builtin_bit_cast(float, u);
}
__device__ inline float gelu_tanh(float x) {
  float x3 = x * x * x;
  return 0.5f * x * (1.0f + tanhf(0.79788456080286536f * (x + 0.044715f * x3)));
}

// ---------------- fused prep ----------------
// b<1792: weight transposes (0=Wq,1=Wk,2=Wv,3=Wqe(fused),4=Wsk,5=W1,6=W2)
// b<1797: ball[1280]; b<1829: WeT; b<2064: zero deg/cursor; else x->bf16
__global__ __launch_bounds__(256) void prep_kernel(
    const float* __restrict__ Wq, const float* __restrict__ Wk, const float* __restrict__ Wv,
    const float* __restrict__ Wsk, const float* __restrict__ W1, const float* __restrict__ W2,
    const float* __restrict__ We, const float* __restrict__ bq, const float* __restrict__ bk,
    const float* __restrict__ bv, const float* __restrict__ x,
    __bf16* __restrict__ WTall, __bf16* __restrict__ WT1, __bf16* __restrict__ WT2,
    float* __restrict__ ball, float* __restrict__ WeT, int* __restrict__ deg,
    __bf16* __restrict__ xb) {
  const int b = blockIdx.x;
  const int tid = threadIdx.x;
  if (b < 1792) {
    const int region = b >> 8;
    const int idx = ((b & 255) << 8) | tid;  // [n(8b)|k(8b)] -> Wt[n][k]
    const int k = idx & 255, n = idx >> 8;
    float v;
    if (region == 3) {  // Wqe on the fly: n = h*32+d
      const int h = n >> 5, d = n & 31;
      const float* wq = Wq + (size_t)k * 256 + h * 32;
      const float* we = We + (size_t)d * 256 + h * 32;
      float s = 0.f;
#pragma unroll
      for (int c = 0; c < 32; ++c) s += wq[c] * we[c];
      v = s;
    } else {
      const float* W = (region == 0) ? Wq : (region == 1) ? Wk : (region == 2) ? Wv
                     : (region == 4) ? Wsk : (region == 5) ? W1 : W2;
      v = W[(size_t)k * 256 + n];
    }
    const __bf16 bv16 = f2bf(v);
    if (region < 5) WTall[(size_t)region * 65536 + idx] = bv16;
    else if (region == 5) WT1[idx] = bv16;
    else WT2[idx] = bv16;
  } else if (b < 1797) {
    const int j = (b - 1792) * 256 + tid;
    if (j < 1280) {
      float v = 0.f;
      if (j < 256) v = bq[j];
      else if (j < 512) v = bk[j - 256];
      else if (j < 768) v = bv[j - 512];
      else if (j < 1024) {
        const int col = j - 768, h = col >> 5, d = col & 31;
        const float* bqh = bq + h * 32;
        const float* we = We + (size_t)d * 256 + h * 32;
        float s = 0.f;
#pragma unroll
        for (int c = 0; c < 32; ++c) s += bqh[c] * we[c];
        v = s;
      }
      ball[j] = v;
    }
  } else if (b < 1829) {
    const int idx = (b - 1797) * 256 + tid;  // < 8192
    const int ch = idx >> 5, d = idx & 31;
    WeT[idx] = We[(size_t)d * 256 + ch];
  } else if (b < 2064) {
    const int i = (b - 1829) * 256 + tid;
    if (i < 2 * NN) deg[i] = 0;
  } else {
    const int t = (b - 2064) * 256 + tid;
    if (t < NN * 256 / 8) {
      const float* p = x + (size_t)t * 8;
      float4v f0 = *(const float4v*)(p);
      float4v f1 = *(const float4v*)(p + 4);
      bf16x8 o;
#pragma unroll
      for (int j = 0; j < 4; ++j) { o[j] = f2bf(f0[j]); o[j + 4] = f2bf(f1[j]); }
      *(bf16x8*)(xb + (size_t)t * 8) = o;
    }
  }
}

// ---------------- CSR build ----------------
__global__ void count_deg_kernel(const int* __restrict__ dst, int* __restrict__ deg, int E) {
  int e = blockIdx.x * 256 + threadIdx.x;
  if (e < E) atomicAdd(&deg[dst[e]], 1);
}

__global__ __launch_bounds__(1024) void scan_kernel(const int* __restrict__ deg,
                                                    int* __restrict__ offs, int n) {
  __shared__ int part[1024];
  const int tid = threadIdx.x;
  const int per = (n + 1023) / 1024;
  const int base = tid * per;
  int s = 0;
  for (int j = 0; j < per; ++j) {
    int i = base + j;
    if (i < n) s += deg[i];
  }
  part[tid] = s;
  __syncthreads();
  for (int st = 1; st < 1024; st <<= 1) {
    int t = (tid >= st) ? part[tid - st] : 0;
    __syncthreads();
    part[tid] += t;
    __syncthreads();
  }
  int run = (tid > 0) ? part[tid - 1] : 0;
  for (int j = 0; j < per; ++j) {
    int i = base + j;
    if (i < n) { offs[i] = run; run += deg[i]; }
  }
  if (tid == 1023) offs[n] = part[1023];
}

__global__ void scatter_kernel(const int* __restrict__ srcIn, const int* __restrict__ dstIn,
                               const int* __restrict__ offs, int* __restrict__ cursor,
                               int* __restrict__ srcs, int* __restrict__ eids, int E) {
  int e = blockIdx.x * 256 + threadIdx.x;
  if (e >= E) return;
  int d = dstIn[e];
  int p = atomicAdd(&cursor[d], 1);
  int o = offs[d] + p;
  srcs[o] = srcIn[e];
  eids[o] = e;
}

// eaC[o][0..32) = bf16(ea[eids[o]][0..32))
__global__ void gather_ea_kernel(const float* __restrict__ ea, const int* __restrict__ eids,
                                 __bf16* __restrict__ eaC, int E) {
  int t = blockIdx.x * 256 + threadIdx.x;
  if (t >= E * 4) return;
  int o = t >> 2, part = t & 3;
  int e = eids[o];
  const float* src = ea + (size_t)e * 32 + part * 8;
  float4v f0 = *(const float4v*)(src);
  float4v f1 = *(const float4v*)(src + 4);
  bf16x8 b;
#pragma unroll
  for (int j = 0; j < 4; ++j) { b[j] = f2bf(f0[j]); b[j + 4] = f2bf(f1[j]); }
  *(bf16x8*)(eaC + (size_t)o * 32 + part * 8) = b;
}

// ---------------- MFMA GEMM v5: DR row-tiles per wave ----------------
// A bf16 [M][256], Wt bf16 [N][256] (N=GX*128). Block = (128*DR) rows x 128
// cols, per-wave 32*DR rows. B^T tile in LDS; after K-loop LDS reused as
// per-wave fp32 C-stage (32x132), DR halves sequentially, coalesced stores.
// MODE 0: EPI 1=fp32, 2=+bias gelu bf16, 3=+bias gelu +resid fp32.
// MODE 1 (GX=10): planes 0..3 -> QG/KV interleaved bf16, plane 4 -> skip fp32.
template <int GX, int EPI, int MODE, int DR>
__global__ __launch_bounds__(256) void gemm_k5(
    const __bf16* __restrict__ A, const __bf16* __restrict__ Wt,
    const float* __restrict__ bias,
    float* __restrict__ Yf, __bf16* __restrict__ Ybf,
    __bf16* __restrict__ QGp, __bf16* __restrict__ KVp,
    const float* __restrict__ resid, int M, int gyTiles) {
  __shared__ char smem[128 * 264 * 2];  // 67584 B
  __bf16* Bs = (__bf16*)smem;
  const int bid = blockIdx.x;
  const int stripe = bid / (8 * GX);
  const int rem = bid % (8 * GX);
  const int y8 = rem % 8;   // XCD id
  const int xt = rem / 8;
  const int y = stripe * 8 + y8;
  if (y >= gyTiles) return;
  const int n0 = xt * 128;

  {
    const int t = threadIdx.x;
#pragma unroll
    for (int i = 0; i < 16; ++i) {
      int g = i * 256 + t;
      int row = g >> 5;
      int c16 = g & 31;
      bf16x8 v = *(const bf16x8*)(Wt + (size_t)(n0 + row) * 256 + c16 * 8);
      *(bf16x8*)(Bs + row * 264 + c16 * 8) = v;
    }
  }
  __syncthreads();

  const int lane = threadIdx.x & 63;
  const int w = threadIdx.x >> 6;
  const int r = lane & 15;
  const int q = lane >> 4;
  const int mw = y * (128 * DR) + w * (32 * DR);
  int ar[2 * DR];
#pragma unroll
  for (int i = 0; i < 2 * DR; ++i) {
    ar[i] = mw + i * 16 + r;
    if (ar[i] >= M) ar[i] = M - 1;
  }
  const int kq = q * 8;

  float4v acc[2 * DR][8];
#pragma unroll
  for (int i = 0; i < 2 * DR; ++i)
#pragma unroll
    for (int t = 0; t < 8; ++t) acc[i][t] = (float4v){0.f, 0.f, 0.f, 0.f};

#pragma unroll
  for (int kk = 0; kk < 256; kk += 32) {
    const int ka = kk + kq;
    bf16x8 a[2 * DR];
#pragma unroll
    for (int i = 0; i < 2 * DR; ++i)
      a[i] = *(const bf16x8*)(A + (size_t)ar[i] * 256 + ka);
    bf16x8 b[8];
#pragma unroll
    for (int t = 0; t < 8; ++t)
      b[t] = *(const bf16x8*)(Bs + (t * 16 + r) * 264 + ka);
#pragma unroll
    for (int t = 0; t < 8; ++t)
#pragma unroll
      for (int i = 0; i < 2 * DR; ++i)
        acc[i][t] = __builtin_amdgcn_mfma_f32_16x16x32_bf16(a[i], b[t], acc[i][t], 0, 0, 0);
  }
  __syncthreads();  // B-tile dead; reuse LDS as C-stage

  float* cs = (float*)smem + w * 4224;
  constexpr int NSTR = GX * 128;
  const int p = n0 >> 8;
  const int cbase = n0 & 255;
  __bf16* dstI = (p == 0 || p == 3) ? QGp : KVp;
  const int moff = (p >= 2) ? 4 : 0;

#pragma unroll
  for (int h = 0; h < DR; ++h) {
#pragma unroll
    for (int t = 0; t < 8; ++t) {
      const int col = n0 + t * 16 + r;
      const float bb = bias ? bias[col] : 0.0f;
#pragma unroll
      for (int i2 = 0; i2 < 2; ++i2)
#pragma unroll
        for (int ii = 0; ii < 4; ++ii) {
          float v = acc[h * 2 + i2][t][ii] + bb;
          if constexpr (EPI == 2 || EPI == 3) v = gelu_tanh(v);
          cs[(i2 * 16 + q * 4 + ii) * 132 + t * 16 + r] = v;
        }
    }
#pragma unroll
    for (int i = 0; i < 16; ++i) {
      const int rl = i * 2 + (lane >> 5);
      const int row = mw + h * 32 + rl;
      const int c4 = (lane & 31) * 4;
      float4v v = *(const float4v*)(cs + rl * 132 + c4);
      if (row < M) {
        if constexpr (MODE == 1) {
          if (p == 4) {
            *(float4v*)(Yf + (size_t)row * 256 + cbase + c4) = v;
          } else {
            bf16x4 b4;
            b4[0] = f2bf(v[0]); b4[1] = f2bf(v[1]); b4[2] = f2bf(v[2]); b4[3] = f2bf(v[3]);
            const int c = cbase + c4;
            *(bf16x4*)(dstI + (size_t)row * 512 + 2 * c + moff) = b4;
          }
        } else if constexpr (EPI == 1) {
          *(float4v*)(Yf + (size_t)row * NSTR + n0 + c4) = v;
        } else if constexpr (EPI == 3) {
          float4v rr = *(const float4v*)(resid + (size_t)row * NSTR + n0 + c4);
          v[0] += rr[0]; v[1] += rr[1]; v[2] += rr[2]; v[3] += rr[3];
          *(float4v*)(Yf + (size_t)row * NSTR + n0 + c4) = v;
        } else {
          bf16x4 b4;
          b4[0] = f2bf(v[0]); b4[1] = f2bf(v[1]); b4[2] = f2bf(v[2]); b4[3] = f2bf(v[3]);
          *(bf16x4*)(Ybf + (size_t)row * NSTR + n0 + c4) = b4;
        }
      }
    }
  }
}

// ---------------- attention + post fused: one block (4 waves) per dst node ---
// Plain exp (no max-sub). Lane owns channels c0=lane*4 (head hg=lane>>3) and
// edge-dims (lane&7)*4 of its head. Epilogue (wave 0): merge wave states,
// share ae*inv across the head group via LDS, add (ae@We) with register-held
// WeT rows, write OUT (fp32, skip+attn) and OUTh (bf16 copy for MLP1).
__global__ __launch_bounds__(256) void attn_kernel(
    const __bf16* __restrict__ QG, const __bf16* __restrict__ KV,
    const __bf16* __restrict__ eaC, const float* __restrict__ WeT,
    const int* __restrict__ offs, const int* __restrict__ srcs,
    float* __restrict__ OUT, __bf16* __restrict__ OUTh) {
  __shared__ float sdn[4][64];
  __shared__ float sav[4][64][4], sae[4][64][4];
  const int lane = threadIdx.x & 63;
  const int w = threadIdx.x >> 6;
  const int n = blockIdx.x;
  const int c0 = lane * 4;
  const int sub = lane & 7;

  const bf16x8 qg = *(const bf16x8*)(QG + (size_t)n * 512 + lane * 8);
  const float q0 = bf2f(qg[0]), q1 = bf2f(qg[1]), q2 = bf2f(qg[2]), q3 = bf2f(qg[3]);
  const float g0 = bf2f(qg[4]), g1 = bf2f(qg[5]), g2 = bf2f(qg[6]), g3 = bf2f(qg[7]);

  float denom = 0.f;
  float4v accv = {0.f, 0.f, 0.f, 0.f};
  float4v acce = {0.f, 0.f, 0.f, 0.f};
  const int beg = offs[n], end = offs[n + 1];
  for (int i = beg + w; i < end; i += 4) {
    const int sn = srcs[i];
    const bf16x8 kv = *(const bf16x8*)(KV + (size_t)sn * 512 + lane * 8);
    const bf16x4 e4 = *(const bf16x4*)(eaC + (size_t)i * 32 + sub * 4);
    const float e0 = bf2f(e4[0]), e1 = bf2f(e4[1]), e2 = bf2f(e4[2]), e3 = bf2f(e4[3]);
    float part = q0 * bf2f(kv[0]) + q1 * bf2f(kv[1]) + q2 * bf2f(kv[2]) + q3 * bf2f(kv[3])
               + g0 * e0 + g1 * e1 + g2 * e2 + g3 * e3;
    part += __shfl_xor(part, 1);
    part += __shfl_xor(part, 2);
    part += __shfl_xor(part, 4);
    const float wgt = __expf(part * 0.17677669529663687f);  // 1/sqrt(32)
    denom += wgt;
    accv[0] += wgt * bf2f(kv[4]);
    accv[1] += wgt * bf2f(kv[5]);
    accv[2] += wgt * bf2f(kv[6]);
    accv[3] += wgt * bf2f(kv[7]);
    acce[0] += wgt * e0;
    acce[1] += wgt * e1;
    acce[2] += wgt * e2;
    acce[3] += wgt * e3;
  }
  sdn[w][lane] = denom;
#pragma unroll
  for (int j = 0; j < 4; ++j) { sav[w][lane][j] = accv[j]; sae[w][lane][j] = acce[j]; }
  __syncthreads();
  if (w == 0) {
    float D = 0.f;
    float4v av = {0.f, 0.f, 0.f, 0.f};
    float4v ae = {0.f, 0.f, 0.f, 0.f};
#pragma unroll
    for (int ww = 0; ww < 4; ++ww) {
      D += sdn[ww][lane];
#pragma unroll
      for (int j = 0; j < 4; ++j) { av[j] += sav[ww][lane][j]; ae[j] += sae[ww][lane][j]; }
    }
    const float inv = 1.0f / (D + 1e-16f);
    // share normalized ae across the 8-lane head group (wave-local LDS)
#pragma unroll
    for (int j = 0; j < 4; ++j) sae[0][lane][j] = ae[j] * inv;
    float4v w4[4][8];
#pragma unroll
    for (int j = 0; j < 4; ++j)
#pragma unroll
      for (int s = 0; s < 8; ++s)
        w4[j][s] = *(const float4v*)(WeT + (size_t)(c0 + j) * 32 + s * 4);
    const int hb = lane & ~7;  // head base lane
    float dotv[4] = {0.f, 0.f, 0.f, 0.f};
#pragma unroll
    for (int s = 0; s < 8; ++s) {
      const float a0 = sae[0][hb + s][0], a1 = sae[0][hb + s][1];
      const float a2 = sae[0][hb + s][2], a3 = sae[0][hb + s][3];
#pragma unroll
      for (int j = 0; j < 4; ++j)
        dotv[j] += a0 * w4[j][s][0] + a1 * w4[j][s][1] + a2 * w4[j][s][2] + a3 * w4[j][s][3];
    }
    float4v o = *(const float4v*)(OUT + (size_t)n * 256 + c0);
#pragma unroll
    for (int j = 0; j < 4; ++j) o[j] += av[j] * inv + dotv[j];
    *(float4v*)(OUT + (size_t)n * 256 + c0) = o;
    bf16x4 ob;
    ob[0] = f2bf(o[0]); ob[1] = f2bf(o[1]); ob[2] = f2bf(o[2]); ob[3] = f2bf(o[3]);
    *(bf16x4*)(OUTh + (size_t)n * 256 + c0) = ob;
  }
}

extern "C" void kernel_launch(void* const* d_in, const int* in_sizes, int n_in,
                              void* d_out, int out_size, void* d_ws, size_t ws_size,
                              hipStream_t stream) {
  (void)in_sizes; (void)n_in; (void)out_size; (void)ws_size;
  const float* x   = (const float*)d_in[0];
  const int*   ei  = (const int*)d_in[1];
  const float* ea  = (const float*)d_in[2];
  const float* Wq  = (const float*)d_in[3];
  const float* bq  = (const float*)d_in[4];
  const float* Wk  = (const float*)d_in[5];
  const float* bk  = (const float*)d_in[6];
  const float* Wv  = (const float*)d_in[7];
  const float* bv  = (const float*)d_in[8];
  const float* We  = (const float*)d_in[9];
  const float* Wsk = (const float*)d_in[10];
  const float* W1  = (const float*)d_in[11];
  const float* b1  = (const float*)d_in[12];
  const float* W2  = (const float*)d_in[13];
  const float* b2  = (const float*)d_in[14];
  float* out = (float*)d_out;

  char* ws = (char*)d_ws;
  size_t off = 0;
  auto alloc = [&](size_t bytes) -> char* {
    off = (off + 255) & ~(size_t)255;
    char* p = ws + off;
    off += bytes;
    return p;
  };
  __bf16* QG   = (__bf16*)alloc((size_t)NN * 512 * 2);
  __bf16* KV   = (__bf16*)alloc((size_t)NN * 512 * 2);
  __bf16* xb   = (__bf16*)alloc((size_t)NN * 256 * 2);
  __bf16* OUTh = (__bf16*)alloc((size_t)NN * 256 * 2);
  __bf16* H1   = (__bf16*)alloc((size_t)NN * 256 * 2);
  __bf16* eaC  = (__bf16*)alloc((size_t)NE * 32 * 2);
  __bf16* WTall = (__bf16*)alloc((size_t)1280 * 256 * 2);
  __bf16* WT1  = (__bf16*)alloc(256 * 256 * 2);
  __bf16* WT2  = (__bf16*)alloc(256 * 256 * 2);
  float*  ball = (float*)alloc(1280 * 4);
  float*  WeT  = (float*)alloc(256 * 32 * 4);
  int* deg    = (int*)alloc((size_t)2 * NN * 4);
  int* cursor = deg + NN;
  int* offs   = (int*)alloc((size_t)(NN + 1) * 4);
  int* srcs   = (int*)alloc((size_t)NE * 4);
  int* eids   = (int*)alloc((size_t)NE * 4);

  const int* srcIn = ei;       // edge_index[0]
  const int* dstIn = ei + NE;  // edge_index[1]

  // ---- fused prep (weights + biases + WeT + zero deg/cursor + x->bf16) ----
  const int prepBlocks = 2064 + (NN * 256 / 8 + 255) / 256;
  prep_kernel<<<prepBlocks, 256, 0, stream>>>(Wq, Wk, Wv, Wsk, W1, W2, We, bq, bk, bv, x,
                                              WTall, WT1, WT2, ball, WeT, deg, xb);

  // ---- CSR build + CSR-ordered edge attrs ----
  count_deg_kernel<<<(NE + 255) / 256, 256, 0, stream>>>(dstIn, deg, NE);
  scan_kernel<<<1, 1024, 0, stream>>>(deg, offs, NN);
  scatter_kernel<<<(NE + 255) / 256, 256, 0, stream>>>(srcIn, dstIn, offs, cursor, srcs, eids, NE);
  gather_ea_kernel<<<(NE * 4 + 255) / 256, 256, 0, stream>>>(ea, eids, eaC, NE);

  // ---- fused node GEMM (DR=2): Q|K|V|QE -> QG/KV interleaved, skip -> out ----
  const int gy2 = (NN + 255) / 256;          // 118
  const int stripes2 = (gy2 + 7) / 8;        // 15
  gemm_k5<10, 0, 1, 2><<<stripes2 * 80, 256, 0, stream>>>(
      xb, WTall, ball, out, nullptr, QG, KV, nullptr, NN, gy2);

  // ---- attention + post (RMW out, write OUTh) ----
  attn_kernel<<<NN, 256, 0, stream>>>(QG, KV, eaC, WeT, offs, srcs, out, OUTh);

  // ---- MLP ----
  const int gy = (NN + 127) / 128;           // 235
  const int stripes = (gy + 7) / 8;          // 30
  gemm_k5<2, 2, 0, 1><<<stripes * 16, 256, 0, stream>>>(
      OUTh, WT1, b1, nullptr, H1, nullptr, nullptr, nullptr, NN, gy);
  gemm_k5<2, 3, 0, 1><<<stripes * 16, 256, 0, stream>>>(
      H1, WT2, b2, out, nullptr, nullptr, nullptr, out, NN, gy);
}